// Round 2
// baseline (485.092 us; speedup 1.0000x reference)
//
#include <hip/hip_runtime.h>
#include <hip/hip_bf16.h>

// ---------------------------------------------------------------------------
// MHA forward: x[4,2048,768] @ w_qkv[768,2304] -> split heads -> softmax(QK^T/8)V
//              -> @ w_proj[768,768] + b_proj. fp32 in/out, bf16 MFMA internally.
// Round 2: log2-domain flash attention, KBLK=64, ones-MFMA row sums,
//          defer-max rescale, XOR-swizzled P buffer. Q pre-scaled by 1/8*log2e.
// ---------------------------------------------------------------------------

typedef short s16x8 __attribute__((ext_vector_type(8)));   // 8 bf16 bit-patterns (4 VGPR)
typedef short s16x4 __attribute__((ext_vector_type(4)));   // 4 bf16 (8B)
typedef float f32x4 __attribute__((ext_vector_type(4)));

#define NHEADS 12
#define HDIM   64
#define SEQ    2048
#define BATCH  4
#define DMODEL 768
#define MTOT   (BATCH*SEQ)     /* 8192 */
#define K3     (3*DMODEL)      /* 2304 */
#define QSCALE 0.18033688f     /* 0.125 * log2(e): logits in log2 domain */

__device__ __forceinline__ short f2bf(float f) {
  return __builtin_bit_cast(short, __float2bfloat16(f));
}

__device__ __forceinline__ f32x4 mfma16(s16x8 a, s16x8 b, f32x4 c) {
  return __builtin_amdgcn_mfma_f32_16x16x32_bf16(a, b, c, 0, 0, 0);
}

// ---- cast fp32 -> bf16, 4 elems/thread, vectorized -------------------------
__global__ __launch_bounds__(256) void k_cast4(const float* __restrict__ in,
                                               short* __restrict__ out, int n4) {
  int i = blockIdx.x * 256 + threadIdx.x;
  if (i < n4) {
    float4 f = reinterpret_cast<const float4*>(in)[i];
    s16x4 v;
    v[0] = f2bf(f.x); v[1] = f2bf(f.y); v[2] = f2bf(f.z); v[3] = f2bf(f.w);
    reinterpret_cast<s16x4*>(out)[i] = v;
  }
}

// ---- transposed cast: in[768][C] fp32 -> out[C][768] bf16 ------------------
__global__ __launch_bounds__(256) void k_transpose768(const float* __restrict__ in,
                                                      short* __restrict__ out, int C) {
  int o = blockIdx.x * 256 + threadIdx.x;   // o = c*768 + r  (coalesced writes)
  if (o < C * DMODEL) {
    int c = o / DMODEL;
    int r = o - c * DMODEL;
    out[o] = f2bf(in[r * C + c]);
  }
}

// ---- QKV GEMM: Xb[8192][768] @ WqkvT[2304][768]^T, scatter epilogue --------
// 64x64 tile, BK=32, 4 waves each computing a 32x32 quadrant (2x2 16x16 frags)
__global__ __launch_bounds__(256) void k_gemm_qkv(const short* __restrict__ Xb,
                                                  const short* __restrict__ WT,
                                                  short* __restrict__ Qb,
                                                  short* __restrict__ Kb,
                                                  short* __restrict__ Vt) {
  __shared__ short As[64][40];   // pad +8: 2-way bank alias (free)
  __shared__ short Bs[64][40];
  const int tid = threadIdx.x;
  const int m0 = blockIdx.y * 64, n0 = blockIdx.x * 64;
  const int lane = tid & 63, w = tid >> 6;
  const int wr = w >> 1, wc = w & 1;
  const int g = lane >> 4, r16 = lane & 15;
  const int lr = tid >> 2;            // staging row 0..63
  const int lk = (tid & 3) * 8;       // staging k-offset {0,8,16,24}

  f32x4 acc[2][2] = {};

  for (int k0 = 0; k0 < DMODEL; k0 += 32) {
    s16x8 av = *reinterpret_cast<const s16x8*>(&Xb[(m0 + lr) * DMODEL + k0 + lk]);
    s16x8 bv = *reinterpret_cast<const s16x8*>(&WT[(n0 + lr) * DMODEL + k0 + lk]);
    __syncthreads();
    *reinterpret_cast<s16x8*>(&As[lr][lk]) = av;
    *reinterpret_cast<s16x8*>(&Bs[lr][lk]) = bv;
    __syncthreads();
    s16x8 a0 = *reinterpret_cast<const s16x8*>(&As[wr * 32 + r16][g * 8]);
    s16x8 a1 = *reinterpret_cast<const s16x8*>(&As[wr * 32 + 16 + r16][g * 8]);
    s16x8 b0 = *reinterpret_cast<const s16x8*>(&Bs[wc * 32 + r16][g * 8]);
    s16x8 b1 = *reinterpret_cast<const s16x8*>(&Bs[wc * 32 + 16 + r16][g * 8]);
    acc[0][0] = mfma16(a0, b0, acc[0][0]);
    acc[0][1] = mfma16(a0, b1, acc[0][1]);
    acc[1][0] = mfma16(a1, b0, acc[1][0]);
    acc[1][1] = mfma16(a1, b1, acc[1][1]);
  }

  // epilogue: Q (pre-scaled, log2 domain) / K / V^T[b,h,d,n]
  for (int i = 0; i < 2; ++i) {
    for (int jn = 0; jn < 2; ++jn) {
      const int c = n0 + wc * 32 + jn * 16 + r16;   // wave-uniform 64-col segments
      for (int rr = 0; rr < 4; ++rr) {
        const int m = m0 + wr * 32 + i * 16 + g * 4 + rr;
        const float a = acc[i][jn][rr];
        const int bb = m >> 11, ns = m & 2047;
        if (c < DMODEL) {
          const int h = c >> 6, d = c & 63;
          Qb[((bb * NHEADS + h) * SEQ + ns) * HDIM + d] = f2bf(a * QSCALE);
        } else if (c < 2 * DMODEL) {
          const int cc = c - DMODEL, h = cc >> 6, d = cc & 63;
          Kb[((bb * NHEADS + h) * SEQ + ns) * HDIM + d] = f2bf(a);
        } else {
          const int cc = c - 2 * DMODEL, h = cc >> 6, d = cc & 63;
          Vt[((bb * NHEADS + h) * HDIM + d) * SEQ + ns] = f2bf(a);
        }
      }
    }
  }
}

// ---- flash attention: per wave one 16-row q tile, KBLK=64, log2 domain -----
// No barriers: the 4 waves are independent (wave-private P buffers).
__global__ __launch_bounds__(256) void k_attn(const short* __restrict__ Qb,
                                              const short* __restrict__ Kb,
                                              const short* __restrict__ Vt,
                                              short* __restrict__ Ctx) {
  __shared__ short Pl[4][16 * 64];   // per-wave P tile [16 rows][64 keys], XOR-swizzled
  const int tid = threadIdx.x, lane = tid & 63, w = tid >> 6;
  const int g = lane >> 4, r16 = lane & 15;
  const int bh = blockIdx.y;                 // 0..47
  const int bb = bh / NHEADS, h = bh - bb * NHEADS;
  const int q0 = blockIdx.x * 64 + w * 16;

  const short* Qp = Qb + (size_t)bh * SEQ * HDIM;
  const short* Kp = Kb + (size_t)bh * SEQ * HDIM;
  const short* Vp = Vt + (size_t)bh * HDIM * SEQ;
  short* Pw = Pl[w];

  // Q fragments (row = r16, d slots g*8.. ; Q pre-scaled by 0.125*log2e)
  s16x8 aq0 = *reinterpret_cast<const s16x8*>(&Qp[(q0 + r16) * HDIM + g * 8]);
  s16x8 aq1 = *reinterpret_cast<const s16x8*>(&Qp[(q0 + r16) * HDIM + 32 + g * 8]);

  s16x8 ones;
#pragma unroll
  for (int i = 0; i < 8; ++i) ones[i] = (short)0x3F80;   // bf16 1.0

  float mrun[4];
  f32x4 accv[4] = {};
  f32x4 sacc = {};                        // row sums via ones-MFMA
#pragma unroll
  for (int rr = 0; rr < 4; ++rr) mrun[rr] = -1e30f;

  const int psw_r = (r16 & 7) << 3;       // read-side swizzle for this lane

  for (int kb = 0; kb < SEQ; kb += 64) {
    // ---- QK^T: 64 keys, 8 MFMA --------------------------------------------
    f32x4 s0 = {}, s1 = {}, s2 = {}, s3 = {};
#define QKJ(SJ, J)                                                             \
    {                                                                          \
      const short* kp_ = Kp + (size_t)(kb + (J) * 16 + r16) * HDIM + g * 8;    \
      s16x8 b0_ = *reinterpret_cast<const s16x8*>(kp_);                        \
      s16x8 b1_ = *reinterpret_cast<const s16x8*>(kp_ + 32);                   \
      SJ = mfma16(aq0, b0_, SJ);                                               \
      SJ = mfma16(aq1, b1_, SJ);                                               \
    }
    QKJ(s0, 0) QKJ(s1, 1) QKJ(s2, 2) QKJ(s3, 3)
#undef QKJ

    // ---- issue V loads early (in flight during softmax) -------------------
#define VLD(D)                                                                 \
    const short* vp##D = Vp + (size_t)((D) * 16 + r16) * SEQ + kb + g * 8;     \
    s16x8 va##D = *reinterpret_cast<const s16x8*>(vp##D);                      \
    s16x8 vb##D = *reinterpret_cast<const s16x8*>(vp##D + 32);
    VLD(0) VLD(1) VLD(2) VLD(3)
#undef VLD

    // ---- online softmax (log2 domain) -------------------------------------
    float rowmax[4];
#pragma unroll
    for (int rr = 0; rr < 4; ++rr) {
      float mx = fmaxf(fmaxf(s0[rr], s1[rr]), fmaxf(s2[rr], s3[rr]));
      mx = fmaxf(mx, __shfl_xor(mx, 1));
      mx = fmaxf(mx, __shfl_xor(mx, 2));
      mx = fmaxf(mx, __shfl_xor(mx, 4));
      mx = fmaxf(mx, __shfl_xor(mx, 8));
      rowmax[rr] = mx;
    }
    bool need = (rowmax[0] > mrun[0] + 8.f) | (rowmax[1] > mrun[1] + 8.f) |
                (rowmax[2] > mrun[2] + 8.f) | (rowmax[3] > mrun[3] + 8.f);
    if (__any(need)) {                    // rare: rescale accumulators
#pragma unroll
      for (int rr = 0; rr < 4; ++rr) {
        float mnew = fmaxf(mrun[rr], rowmax[rr]);
        float al = __builtin_amdgcn_exp2f(mrun[rr] - mnew);
        accv[0][rr] *= al; accv[1][rr] *= al;
        accv[2][rr] *= al; accv[3][rr] *= al;
        sacc[rr] *= al;
        mrun[rr] = mnew;
      }
    }
#pragma unroll
    for (int rr = 0; rr < 4; ++rr) {
      const float m = mrun[rr];
      const int prow = g * 4 + rr;
      const int pb = prow * 64 + r16;
      const int ps = (prow & 7) << 3;
      Pw[(pb)      ^ ps] = f2bf(__builtin_amdgcn_exp2f(s0[rr] - m));
      Pw[(pb + 16) ^ ps] = f2bf(__builtin_amdgcn_exp2f(s1[rr] - m));
      Pw[(pb + 32) ^ ps] = f2bf(__builtin_amdgcn_exp2f(s2[rr] - m));
      Pw[(pb + 48) ^ ps] = f2bf(__builtin_amdgcn_exp2f(s3[rr] - m));
    }

    // ---- PV + row sums: 10 MFMA -------------------------------------------
    s16x8 pa0 = *reinterpret_cast<const s16x8*>(&Pw[(r16 * 64 + g * 8)      ^ psw_r]);
    s16x8 pa1 = *reinterpret_cast<const s16x8*>(&Pw[(r16 * 64 + 32 + g * 8) ^ psw_r]);
    sacc = mfma16(pa0, ones, sacc);
    sacc = mfma16(pa1, ones, sacc);
    accv[0] = mfma16(pa0, va0, accv[0]);  accv[0] = mfma16(pa1, vb0, accv[0]);
    accv[1] = mfma16(pa0, va1, accv[1]);  accv[1] = mfma16(pa1, vb1, accv[1]);
    accv[2] = mfma16(pa0, va2, accv[2]);  accv[2] = mfma16(pa1, vb2, accv[2]);
    accv[3] = mfma16(pa0, va3, accv[3]);  accv[3] = mfma16(pa1, vb3, accv[3]);
  }

  // write context [b][n][h*64+d] bf16
#pragma unroll
  for (int dc = 0; dc < 4; ++dc) {
#pragma unroll
    for (int rr = 0; rr < 4; ++rr) {
      float o = accv[dc][rr] / sacc[rr];
      Ctx[(size_t)(bb * SEQ + q0 + g * 4 + rr) * DMODEL + h * HDIM + dc * 16 + r16] = f2bf(o);
    }
  }
}

// ---- proj GEMM: Ctx[8192][768] @ WprojT[768][768]^T + bias -> fp32 out -----
__global__ __launch_bounds__(256) void k_gemm_proj(const short* __restrict__ Ctx,
                                                   const short* __restrict__ WT,
                                                   const float* __restrict__ bias,
                                                   float* __restrict__ Out) {
  __shared__ short As[64][40];
  __shared__ short Bs[64][40];
  const int tid = threadIdx.x;
  const int m0 = blockIdx.y * 64, n0 = blockIdx.x * 64;
  const int lane = tid & 63, w = tid >> 6;
  const int wr = w >> 1, wc = w & 1;
  const int g = lane >> 4, r16 = lane & 15;
  const int lr = tid >> 2;
  const int lk = (tid & 3) * 8;

  f32x4 acc[2][2] = {};

  for (int k0 = 0; k0 < DMODEL; k0 += 32) {
    s16x8 av = *reinterpret_cast<const s16x8*>(&Ctx[(m0 + lr) * DMODEL + k0 + lk]);
    s16x8 bv = *reinterpret_cast<const s16x8*>(&WT[(n0 + lr) * DMODEL + k0 + lk]);
    __syncthreads();
    *reinterpret_cast<s16x8*>(&As[lr][lk]) = av;
    *reinterpret_cast<s16x8*>(&Bs[lr][lk]) = bv;
    __syncthreads();
    s16x8 a0 = *reinterpret_cast<const s16x8*>(&As[wr * 32 + r16][g * 8]);
    s16x8 a1 = *reinterpret_cast<const s16x8*>(&As[wr * 32 + 16 + r16][g * 8]);
    s16x8 b0 = *reinterpret_cast<const s16x8*>(&Bs[wc * 32 + r16][g * 8]);
    s16x8 b1 = *reinterpret_cast<const s16x8*>(&Bs[wc * 32 + 16 + r16][g * 8]);
    acc[0][0] = mfma16(a0, b0, acc[0][0]);
    acc[0][1] = mfma16(a0, b1, acc[0][1]);
    acc[1][0] = mfma16(a1, b0, acc[1][0]);
    acc[1][1] = mfma16(a1, b1, acc[1][1]);
  }

  for (int i = 0; i < 2; ++i) {
    for (int jn = 0; jn < 2; ++jn) {
      const int c = n0 + wc * 32 + jn * 16 + r16;
      const float bv = bias[c];
      for (int rr = 0; rr < 4; ++rr) {
        const int m = m0 + wr * 32 + i * 16 + g * 4 + rr;
        Out[(size_t)m * DMODEL + c] = acc[i][jn][rr] + bv;
      }
    }
  }
}

extern "C" void kernel_launch(void* const* d_in, const int* in_sizes, int n_in,
                              void* d_out, int out_size, void* d_ws, size_t ws_size,
                              hipStream_t stream) {
  const float* x      = (const float*)d_in[0];
  const float* w_qkv  = (const float*)d_in[1];
  const float* w_proj = (const float*)d_in[2];
  const float* b_proj = (const float*)d_in[3];
  float* out = (float*)d_out;

  char* ws = (char*)d_ws;
  const size_t SZ_X = (size_t)MTOT * DMODEL * 2;   // 12.58 MB
  short* Xb     = (short*)ws;                 ws += SZ_X;
  short* WqkvT  = (short*)ws;                 ws += (size_t)K3 * DMODEL * 2;
  short* WprojT = (short*)ws;                 ws += (size_t)DMODEL * DMODEL * 2;
  short* Qb     = (short*)ws;                 ws += SZ_X;
  short* Kb     = (short*)ws;                 ws += SZ_X;
  short* Vt     = (short*)ws;                 ws += SZ_X;
  short* Ctxb   = Xb;   // alias: Xb dead after QKV GEMM

  k_cast4<<<(MTOT * DMODEL / 4) / 256, 256, 0, stream>>>(x, Xb, MTOT * DMODEL / 4);
  k_transpose768<<<(K3 * DMODEL + 255) / 256, 256, 0, stream>>>(w_qkv, WqkvT, K3);
  k_transpose768<<<(DMODEL * DMODEL + 255) / 256, 256, 0, stream>>>(w_proj, WprojT, DMODEL);

  k_gemm_qkv<<<dim3(K3 / 64, MTOT / 64), 256, 0, stream>>>(Xb, WqkvT, Qb, Kb, Vt);
  k_attn<<<dim3(SEQ / 64, BATCH * NHEADS), 256, 0, stream>>>(Qb, Kb, Vt, Ctxb);
  k_gemm_proj<<<dim3(DMODEL / 64, MTOT / 64), 256, 0, stream>>>(Ctxb, WprojT, b_proj, out);
}